// Round 4
// baseline (329.437 us; speedup 1.0000x reference)
//
#include <hip/hip_runtime.h>

typedef __attribute__((ext_vector_type(8))) short short8;
typedef __attribute__((ext_vector_type(4))) float f32x4;
typedef __attribute__((ext_vector_type(4))) unsigned short u16x4;
typedef __attribute__((ext_vector_type(4))) unsigned int u32x4;

#define MFMA16(a,b,c) __builtin_amdgcn_mfma_f32_16x16x32_bf16((a),(b),(c),0,0,0)

// 0.125 (attn scale) * log2(e), folded into Q at the QKV epilogue.
#define QSCALE 0.1803368801f

__device__ __forceinline__ unsigned short f2bf(float f) {
  unsigned int x = __float_as_uint(f);
  x += 0x7fffu + ((x >> 16) & 1u);
  return (unsigned short)(x >> 16);
}
// async 16B global -> LDS (dest = wave-uniform base + lane*16)
__device__ __forceinline__ void gload16(const unsigned short* g, unsigned short* l) {
  __builtin_amdgcn_global_load_lds(
      (const __attribute__((address_space(1))) unsigned int*)g,
      (__attribute__((address_space(3))) unsigned int*)l, 16, 0, 0);
}
// packed f32x2 -> bf16x2 (lo = a, hi = b), single VALU op
__device__ __forceinline__ unsigned int cvtpk(float a, float b) {
  unsigned int r;
  asm("v_cvt_pk_bf16_f32 %0, %1, %2" : "=v"(r) : "v"(a), "v"(b));
  return r;
}

// Fragment-major A layout: elem(m,k) -> xf[((k>>5)*512 + (m>>4))*512 +
// (((k>>3)&3)*16 + (m&15))*8 + (k&7)].  A wave's 16x32 MFMA A-frag (row-tile
// M16, k-block kb) is then 1 KB contiguous: base + lane*16B, one coalesced
// global_load_dwordx4 per lane. 512 = 8192/16 M16-tiles; kb = k/32.

// ---------------------------------------------------------------------------
// Kernel 1: prep = convert x -> frag-major bf16 (blocks < 6144) +
//                  build LoRA-folded weights (rest).
// ---------------------------------------------------------------------------
__global__ __launch_bounds__(256) void prep(
    const float* __restrict__ x,
    const float* __restrict__ w_qkv,
    const float* __restrict__ w_proj,
    const float* __restrict__ q_a, const float* __restrict__ q_b,
    const float* __restrict__ k_a, const float* __restrict__ k_b,
    const float* __restrict__ v_a, const float* __restrict__ v_b,
    const float* __restrict__ o_a, const float* __restrict__ o_b,
    unsigned short* __restrict__ xf,
    unsigned short* __restrict__ wqkv_eff,
    unsigned short* __restrict__ wproj_eff)
{
  int bid = blockIdx.x;
  if (bid < 6144) {
    int i4 = (bid * 256 + threadIdx.x) * 4;
    int m  = i4 / 768;
    int k4 = i4 - m * 768;             // 4 consecutive k, same 8-chunk half
    f32x4 v = *(const f32x4*)&x[i4];
    u16x4 o;
    o.x = f2bf(v.x); o.y = f2bf(v.y); o.z = f2bf(v.z); o.w = f2bf(v.w);
    int kb = k4 >> 5, qd = (k4 >> 3) & 3, j0 = k4 & 7;
    size_t idx = ((size_t)(kb * 512 + (m >> 4)) << 9) +
                 (((qd << 4) + (m & 15)) << 3) + j0;
    *(u16x4*)&xf[idx] = o;
    return;
  }
  const int QKV = 2304 * 768;
  int idx = (bid - 6144) * 256 + threadIdx.x;
  if (idx < QKV) {
    int n = idx / 768, c = idx - n * 768;
    int sec = n / 768;
    int nr = n - sec * 768;
    const float* a; const float* b;
    if (sec == 0)      { a = q_a; b = q_b; }
    else if (sec == 1) { a = k_a; b = k_b; }
    else               { a = v_a; b = v_b; }
    float acc = w_qkv[idx];
    #pragma unroll
    for (int r = 0; r < 8; r++)
      acc += b[nr * 8 + r] * a[r * 768 + c];
    wqkv_eff[idx] = f2bf(acc);
  } else {
    int i2 = idx - QKV;
    int n = i2 / 768, c = i2 - n * 768;
    float acc = w_proj[i2];
    #pragma unroll
    for (int r = 0; r < 8; r++)
      acc += o_b[n * 8 + r] * o_a[r * 768 + c];
    wproj_eff[i2] = f2bf(acc);
  }
}

// ---------------------------------------------------------------------------
// Kernel 2/4: C[M,Ncols] = A@W^T + bias. A in FRAG-MAJOR layout, loaded
// direct global->register (coalesced 1KB/wave), prefetched one iter ahead.
// W via padded-LDS VGPR-roundtrip with register prefetch.
// BM=128, BN=64, BK=64; 4 waves x 32 rows.
// mode 0 (QKV): Q*QSCALE -> q[BH][N][64]; K -> k[BH][N][64];
//               V -> vt[BH][64][1024], key-permuted cols chosen so the attn
//               kernel's in-register P (swapped-QK^T layout) feeds PV directly:
//               within 64: bit5 stays, bits[3:2]->[4:3], bit4->bit2, bits[1:0] stay.
// mode 1: fp32 row-major store (final output).
// ---------------------------------------------------------------------------
__global__ __launch_bounds__(256) void gemm_bt(
    const unsigned short* __restrict__ Af,
    const unsigned short* __restrict__ W,
    const float* __restrict__ bias,
    unsigned short* __restrict__ out0,
    unsigned short* __restrict__ out1,
    unsigned short* __restrict__ out2,
    float* __restrict__ outf,
    int K, int Ncols, int mode)
{
  __shared__ alignas(16) unsigned short Ws[64][72];
  const int tid  = threadIdx.x;
  const int wave = tid >> 6;
  const int lane = tid & 63;
  const int quad = lane >> 4;
  const int l16  = lane & 15;
  const int m0 = blockIdx.x * 128;
  const int n0 = blockIdx.y * 64;
  const int M16b = (m0 >> 4) + wave * 2;       // wave's row-tiles: M16b, M16b+1

  int wr[2], wc[2];
  #pragma unroll
  for (int i = 0; i < 2; i++) { int f = tid + i * 256; wr[i] = f >> 3; wc[i] = (f & 7) << 3; }

  f32x4 wreg[2];
  #pragma unroll
  for (int i = 0; i < 2; i++)
    wreg[i] = *(const f32x4*)&W[(size_t)(n0 + wr[i]) * K + wc[i]];

  short8 aCur[2][2], aNxt[2][2] = {};          // [row-tile t][ks]
  #pragma unroll
  for (int t = 0; t < 2; t++)
    #pragma unroll
    for (int ks = 0; ks < 2; ks++)
      aCur[t][ks] = *(const short8*)&Af[((size_t)(ks * 512 + M16b + t) << 9) + (lane << 3)];

  f32x4 acc[2][4] = {};

  for (int k0 = 0; k0 < K; k0 += 64) {
    __syncthreads();
    #pragma unroll
    for (int i = 0; i < 2; i++) *(f32x4*)&Ws[wr[i]][wc[i]] = wreg[i];
    __syncthreads();
    if (k0 + 64 < K) {
      #pragma unroll
      for (int i = 0; i < 2; i++)
        wreg[i] = *(const f32x4*)&W[(size_t)(n0 + wr[i]) * K + k0 + 64 + wc[i]];
      const int kbn = (k0 + 64) >> 5;
      #pragma unroll
      for (int t = 0; t < 2; t++)
        #pragma unroll
        for (int ks = 0; ks < 2; ks++)
          aNxt[t][ks] = *(const short8*)&Af[((size_t)((kbn + ks) * 512 + M16b + t) << 9) + (lane << 3)];
    }
    #pragma unroll
    for (int ks = 0; ks < 2; ks++) {
      const int kk = ks * 32 + quad * 8;
      short8 b0 = *(const short8*)&Ws[l16][kk];
      short8 b1 = *(const short8*)&Ws[16 + l16][kk];
      short8 b2 = *(const short8*)&Ws[32 + l16][kk];
      short8 b3 = *(const short8*)&Ws[48 + l16][kk];
      acc[0][0] = MFMA16(aCur[0][ks], b0, acc[0][0]);
      acc[0][1] = MFMA16(aCur[0][ks], b1, acc[0][1]);
      acc[0][2] = MFMA16(aCur[0][ks], b2, acc[0][2]);
      acc[0][3] = MFMA16(aCur[0][ks], b3, acc[0][3]);
      acc[1][0] = MFMA16(aCur[1][ks], b0, acc[1][0]);
      acc[1][1] = MFMA16(aCur[1][ks], b1, acc[1][1]);
      acc[1][2] = MFMA16(aCur[1][ks], b2, acc[1][2]);
      acc[1][3] = MFMA16(aCur[1][ks], b3, acc[1][3]);
    }
    #pragma unroll
    for (int t = 0; t < 2; t++)
      #pragma unroll
      for (int ks = 0; ks < 2; ks++)
        aCur[t][ks] = aNxt[t][ks];
  }

  float bv[4];
  #pragma unroll
  for (int j = 0; j < 4; j++) bv[j] = bias[n0 + j * 16 + l16];

  if (mode == 0) {
    const int sec = n0 / 768;
    const int h   = (n0 % 768) >> 6;
    unsigned short* dst = (sec == 0) ? out0 : ((sec == 1) ? out1 : out2);
    const float scl = (sec == 0) ? QSCALE : 1.0f;
    #pragma unroll
    for (int rg = 0; rg < 2; rg++) {
      #pragma unroll
      for (int r = 0; r < 4; r++) {
        int m  = m0 + wave * 32 + rg * 16 + quad * 4 + r;
        int b  = m >> 10, np = m & 1023;
        int bh = b * 12 + h;
        // key perm for swapped-QK^T in-register P (see attn):
        // pos = bit5 | (bits3:2 -> 4:3) | (bit4 -> 2) | bits1:0
        int npp = (np & ~63) | (np & 35) | ((np & 12) << 1) | ((np & 16) >> 2);
        #pragma unroll
        for (int j = 0; j < 4; j++) {
          int d = j * 16 + l16;
          float v = (acc[rg][j][r] + bv[j]) * scl;
          if (sec < 2) dst[((size_t)bh << 16) + ((size_t)np << 6) + d] = f2bf(v);
          else         dst[((size_t)bh << 16) + ((size_t)d << 10) + npp] = f2bf(v);
        }
      }
    }
  } else {
    #pragma unroll
    for (int rg = 0; rg < 2; rg++) {
      #pragma unroll
      for (int r = 0; r < 4; r++) {
        int m = m0 + wave * 32 + rg * 16 + quad * 4 + r;
        #pragma unroll
        for (int j = 0; j < 4; j++)
          outf[(size_t)m * Ncols + n0 + j * 16 + l16] = acc[rg][j][r] + bv[j];
      }
    }
  }
}

// ---------------------------------------------------------------------------
// Kernel 3: flash attention, SWAPPED QK^T (S^T = K x Q): each lane holds a
// lane-local P slice -> PV A-frags built in-register, no P LDS round-trip,
// no Q staging.  QBLK=64 (4 waves x 16 q-rows), grid 96x16 = 1536 blocks.
// Round-4: V staging DROPPED (m169 lesson: V re-reads are L2/L3-absorbed --
// FETCH_SIZE already shows one clean Q+K+V pass). V is read directly from
// global as B-frags (key perm baked into vt by the QKV GEMM; no swizzle
// needed). LDS 32->16 KB: ALL 1536 blocks co-resident (6 blocks/CU,
// 24 waves/CU vs 20); staging gloads halve; barrier drain covers only K.
// __launch_bounds__(256,8) pins VGPR<=64 (m69 occupancy cliff).
// Row-sum denominator via ones-column MFMA (round 3).
// Lane (l16,quad) after QK holds P[q=l16][key=16i+4*quad+r]; the V column
// permutation (gemm mode 0) places key 16i+4q+r at PV A-frag slot
// ks*32 + quad*8 + (i&1)*4 + r with ks=i>>1.
// ---------------------------------------------------------------------------
__global__ __launch_bounds__(256, 8) void attn(
    const unsigned short* __restrict__ q,
    const unsigned short* __restrict__ k,
    const unsigned short* __restrict__ vt,
    unsigned short* __restrict__ of)
{
  __shared__ alignas(16) unsigned short Ks2[2][64 * 64];  // 2 x 8 KB
  const int tid  = threadIdx.x;
  const int wave = tid >> 6;
  const int lane = tid & 63;
  const int quad = lane >> 4;
  const int l16  = lane & 15;
  const int bh = blockIdx.x;
  const int q0 = blockIdx.y * 64;
  const unsigned short* qb = q  + ((size_t)bh << 16);
  const unsigned short* kb = k  + ((size_t)bh << 16);
  const unsigned short* vb = vt + ((size_t)bh << 16);

  const int lrow   = lane >> 3;
  const int lchunk = (lane & 7) ^ lrow;
  const unsigned short* gK[2];
  int lsK[2];
  #pragma unroll
  for (int t = 0; t < 2; t++) {
    int rr = wave * 16 + t * 8 + lrow;
    gK[t]  = kb + (size_t)rr * 64 + lchunk * 8;
    lsK[t] = rr * 64 + (lane & 7) * 8;
  }
  const int swz = l16 & 7;

  #pragma unroll
  for (int t = 0; t < 2; t++)
    gload16(gK[t], &Ks2[0][lsK[t]]);

  // Q B-frags direct from global: B[n=l16][kdim = ks*32 + quad*8 + j]
  short8 bq[2];
  #pragma unroll
  for (int ks = 0; ks < 2; ks++)
    bq[ks] = *(const short8*)&qb[((size_t)(q0 + wave * 16 + l16) << 6) +
                                 ks * 32 + quad * 8];

  // V direct-global per-lane base: row d = j*16 + l16 (stride 16384 shorts
  // per j), col = kt*64 + ks*32 + quad*8 within the permuted key axis.
  const unsigned short* gVd = vb + (size_t)l16 * 1024 + quad * 8;

  // all-ones bf16 B-fragment for the row-sum MFMA
  union { u32x4 w; short8 h; } onesu;
  onesu.w.x = 0x3F803F80u; onesu.w.y = 0x3F803F80u;
  onesu.w.z = 0x3F803F80u; onesu.w.w = 0x3F803F80u;
  const short8 onesb = onesu.h;

  f32x4 Oacc[4] = {};
  f32x4 lacc = {};

  union PAW { u32x4 w; short8 h; };

  for (int kt = 0; kt < 16; kt++) {
    const int p = kt & 1;
    __syncthreads();
    if (kt < 15) {
      #pragma unroll
      for (int t = 0; t < 2; t++)
        gload16(gK[t] + (kt + 1) * 4096, &Ks2[1 - p][lsK[t]]);
    }

    // QK^T swapped: A = K row-tile i (from LDS), B = Q (registers).
    // s[i] reg r = S[key = i*16 + quad*4 + r][q = l16]
    f32x4 s[4] = {};
    #pragma unroll
    for (int ks = 0; ks < 2; ks++) {
      const int cs = ks * 4 + quad;
      short8 a0 = *(const short8*)&Ks2[p][(l16)      * 64 + ((cs ^ swz) << 3)];
      short8 a1 = *(const short8*)&Ks2[p][(16 + l16) * 64 + ((cs ^ swz) << 3)];
      short8 a2 = *(const short8*)&Ks2[p][(32 + l16) * 64 + ((cs ^ swz) << 3)];
      short8 a3 = *(const short8*)&Ks2[p][(48 + l16) * 64 + ((cs ^ swz) << 3)];
      s[0] = MFMA16(a0, bq[ks], s[0]);
      s[1] = MFMA16(a1, bq[ks], s[1]);
      s[2] = MFMA16(a2, bq[ks], s[2]);
      s[3] = MFMA16(a3, bq[ks], s[3]);
    }

    // softmax (no max-subtraction; scale folded into Q) + in-register P frags
    f32x4 e[4];
    #pragma unroll
    for (int i = 0; i < 4; i++) {
      e[i].x = exp2f(s[i].x);
      e[i].y = exp2f(s[i].y);
      e[i].z = exp2f(s[i].z);
      e[i].w = exp2f(s[i].w);
    }
    short8 pa[2];
    #pragma unroll
    for (int ks = 0; ks < 2; ks++) {
      PAW pw;
      pw.w.x = cvtpk(e[2 * ks].x,     e[2 * ks].y);
      pw.w.y = cvtpk(e[2 * ks].z,     e[2 * ks].w);
      pw.w.z = cvtpk(e[2 * ks + 1].x, e[2 * ks + 1].y);
      pw.w.w = cvtpk(e[2 * ks + 1].z, e[2 * ks + 1].w);
      pa[ks] = pw.h;
    }

    // PV: A = P frags (registers), B = V^T read DIRECT from global (L2-hot).
    // 5th MFMA per ks with B=ones accumulates row sums (denominator).
    #pragma unroll
    for (int ks = 0; ks < 2; ks++) {
      const unsigned short* gv = gVd + kt * 64 + ks * 32;
      short8 v0 = *(const short8*)&gv[0];
      short8 v1 = *(const short8*)&gv[16384];
      short8 v2 = *(const short8*)&gv[32768];
      short8 v3 = *(const short8*)&gv[49152];
      Oacc[0] = MFMA16(pa[ks], v0, Oacc[0]);
      Oacc[1] = MFMA16(pa[ks], v1, Oacc[1]);
      Oacc[2] = MFMA16(pa[ks], v2, Oacc[2]);
      Oacc[3] = MFMA16(pa[ks], v3, Oacc[3]);
      lacc    = MFMA16(pa[ks], onesb, lacc);
    }
  }

  // lacc[r] = full row sum for q-row quad*4+r (all l16 cols identical) --
  // already in the C/D indexing the epilogue uses; no cross-lane reduction.
  // O store in FRAG-MAJOR layout (proj GEMM's A-path):
  // row M = b*1024+np -> M16 = b*64 + (np>>4), l16m = np&15;
  // col = h*64 + j*16 + l16 -> kb = col>>5, qc = (col>>3)&3, jj = l16&7.
  const int b = bh / 12, h = bh - (bh / 12) * 12;
  #pragma unroll
  for (int r = 0; r < 4; r++) {
    float inv = 1.0f / lacc[r];
    int np  = q0 + wave * 16 + quad * 4 + r;
    int M16 = b * 64 + (np >> 4);
    int l16m = np & 15;
    #pragma unroll
    for (int j = 0; j < 4; j++) {
      int col = h * 64 + j * 16 + l16;
      int kb2 = col >> 5;
      int qc  = (col >> 3) & 3;
      size_t idx = ((size_t)(kb2 * 512 + M16) << 9) +
                   ((qc * 16 + l16m) << 3) + (l16 & 7);
      of[idx] = f2bf(Oacc[j][r] * inv);
    }
  }
}

// ---------------------------------------------------------------------------
extern "C" void kernel_launch(void* const* d_in, const int* in_sizes, int n_in,
                              void* d_out, int out_size, void* d_ws, size_t ws_size,
                              hipStream_t stream) {
  const float* x      = (const float*)d_in[0];
  const float* w_qkv  = (const float*)d_in[1];
  const float* b_qkv  = (const float*)d_in[2];
  const float* w_proj = (const float*)d_in[3];
  const float* b_proj = (const float*)d_in[4];
  const float* q_a    = (const float*)d_in[5];
  const float* q_b    = (const float*)d_in[6];
  const float* k_a    = (const float*)d_in[7];
  const float* k_b    = (const float*)d_in[8];
  const float* v_a    = (const float*)d_in[9];
  const float* v_b    = (const float*)d_in[10];
  const float* o_a    = (const float*)d_in[11];
  const float* o_b    = (const float*)d_in[12];

  char* ws = (char*)d_ws;
  unsigned short* wqkv_eff  = (unsigned short*)(ws + 0);          // 3,538,944
  unsigned short* wproj_eff = (unsigned short*)(ws + 3538944);    // 1,179,648
  unsigned short* xf        = (unsigned short*)(ws + 4718592);    // 12,582,912 (frag-major; reused as of)
  unsigned short* qd        = (unsigned short*)(ws + 17301504);   // 12,582,912
  unsigned short* kd        = (unsigned short*)(ws + 29884416);   // 12,582,912
  unsigned short* vtd       = (unsigned short*)(ws + 42467328);   // 12,582,912 (end 55,050,240)
  unsigned short* of        = xf;  // xf dead after QKV GEMM

  prep<<<dim3(6144 + 9216), dim3(256), 0, stream>>>(
      x, w_qkv, w_proj, q_a, q_b, k_a, k_b, v_a, v_b, o_a, o_b,
      xf, wqkv_eff, wproj_eff);

  gemm_bt<<<dim3(64, 36), dim3(256), 0, stream>>>(
      xf, wqkv_eff, b_qkv, qd, kd, vtd, nullptr, 768, 2304, 0);

  attn<<<dim3(96, 16), dim3(256), 0, stream>>>(qd, kd, vtd, of);

  gemm_bt<<<dim3(64, 12), dim3(256), 0, stream>>>(
      of, wproj_eff, b_proj, nullptr, nullptr, nullptr, (float*)d_out, 768, 768, 1);
}

// Round 5
// 217.035 us; speedup vs baseline: 1.5179x; 1.5179x over previous
//
#include <hip/hip_runtime.h>

typedef __attribute__((ext_vector_type(8))) short short8;
typedef __attribute__((ext_vector_type(4))) float f32x4;
typedef __attribute__((ext_vector_type(4))) unsigned short u16x4;
typedef __attribute__((ext_vector_type(4))) unsigned int u32x4;

#define MFMA16(a,b,c) __builtin_amdgcn_mfma_f32_16x16x32_bf16((a),(b),(c),0,0,0)

// 0.125 (attn scale) * log2(e), folded into Q at the QKV epilogue.
#define QSCALE 0.1803368801f

__device__ __forceinline__ unsigned short f2bf(float f) {
  unsigned int x = __float_as_uint(f);
  x += 0x7fffu + ((x >> 16) & 1u);
  return (unsigned short)(x >> 16);
}
// packed f32x2 -> bf16x2 (lo = a, hi = b), single VALU op
__device__ __forceinline__ unsigned int cvtpk(float a, float b) {
  unsigned int r;
  asm("v_cvt_pk_bf16_f32 %0, %1, %2" : "=v"(r) : "v"(a), "v"(b));
  return r;
}

// Fragment-major A layout: elem(m,k) -> xf[((k>>5)*512 + (m>>4))*512 +
// (((k>>3)&3)*16 + (m&15))*8 + (k&7)].  A wave's 16x32 MFMA A-frag (row-tile
// M16, k-block kb) is then 1 KB contiguous: base + lane*16B, one coalesced
// global_load_dwordx4 per lane. 512 = 8192/16 M16-tiles; kb = k/32.

// ---------------------------------------------------------------------------
// Kernel 1: prep = convert x -> frag-major bf16 (blocks < 6144) +
//                  build LoRA-folded weights (rest).
// ---------------------------------------------------------------------------
__global__ __launch_bounds__(256) void prep(
    const float* __restrict__ x,
    const float* __restrict__ w_qkv,
    const float* __restrict__ w_proj,
    const float* __restrict__ q_a, const float* __restrict__ q_b,
    const float* __restrict__ k_a, const float* __restrict__ k_b,
    const float* __restrict__ v_a, const float* __restrict__ v_b,
    const float* __restrict__ o_a, const float* __restrict__ o_b,
    unsigned short* __restrict__ xf,
    unsigned short* __restrict__ wqkv_eff,
    unsigned short* __restrict__ wproj_eff)
{
  int bid = blockIdx.x;
  if (bid < 6144) {
    int i4 = (bid * 256 + threadIdx.x) * 4;
    int m  = i4 / 768;
    int k4 = i4 - m * 768;             // 4 consecutive k, same 8-chunk half
    f32x4 v = *(const f32x4*)&x[i4];
    u16x4 o;
    o.x = f2bf(v.x); o.y = f2bf(v.y); o.z = f2bf(v.z); o.w = f2bf(v.w);
    int kb = k4 >> 5, qd = (k4 >> 3) & 3, j0 = k4 & 7;
    size_t idx = ((size_t)(kb * 512 + (m >> 4)) << 9) +
                 (((qd << 4) + (m & 15)) << 3) + j0;
    *(u16x4*)&xf[idx] = o;
    return;
  }
  const int QKV = 2304 * 768;
  int idx = (bid - 6144) * 256 + threadIdx.x;
  if (idx < QKV) {
    int n = idx / 768, c = idx - n * 768;
    int sec = n / 768;
    int nr = n - sec * 768;
    const float* a; const float* b;
    if (sec == 0)      { a = q_a; b = q_b; }
    else if (sec == 1) { a = k_a; b = k_b; }
    else               { a = v_a; b = v_b; }
    float acc = w_qkv[idx];
    #pragma unroll
    for (int r = 0; r < 8; r++)
      acc += b[nr * 8 + r] * a[r * 768 + c];
    wqkv_eff[idx] = f2bf(acc);
  } else {
    int i2 = idx - QKV;
    int n = i2 / 768, c = i2 - n * 768;
    float acc = w_proj[i2];
    #pragma unroll
    for (int r = 0; r < 8; r++)
      acc += o_b[n * 8 + r] * o_a[r * 768 + c];
    wproj_eff[i2] = f2bf(acc);
  }
}

// ---------------------------------------------------------------------------
// Kernel 2/4: C[M,Ncols] = A@W^T + bias. A in FRAG-MAJOR layout, loaded
// direct global->register (coalesced 1KB/wave), prefetched one iter ahead.
// W via padded-LDS VGPR-roundtrip with register prefetch.
// BM=128, BN=64, BK=64; 4 waves x 32 rows.
// mode 0 (QKV): Q*QSCALE -> q[BH][N][64] row-major;
//               K -> A-FRAG-MAJOR per bh: elem(np,d) at
//                    ((np>>4)*2 + d>>5)*512 + (((d>>3)&3)*16 + (np&15))*8 + (d&7)
//               V -> B-FRAG-MAJOR per bh with key perm s(np) folded:
//                    s = (np&35)|((np&12)<<1)|((np&16)>>2)  (within-64 slot);
//                    (((np>>6)*2 + (s>>5))*4 + (d>>4))*512 +
//                    (((s>>3)&3)*16 + (d&15))*8 + (s&7)
//               -> attn reads K/V fragments as coalesced 1KB/wave loads,
//                  straight to registers: NO LDS, NO barriers in attn.
// mode 1: fp32 row-major store (final output).
// ---------------------------------------------------------------------------
__global__ __launch_bounds__(256) void gemm_bt(
    const unsigned short* __restrict__ Af,
    const unsigned short* __restrict__ W,
    const float* __restrict__ bias,
    unsigned short* __restrict__ out0,
    unsigned short* __restrict__ out1,
    unsigned short* __restrict__ out2,
    float* __restrict__ outf,
    int K, int Ncols, int mode)
{
  __shared__ alignas(16) unsigned short Ws[64][72];
  const int tid  = threadIdx.x;
  const int wave = tid >> 6;
  const int lane = tid & 63;
  const int quad = lane >> 4;
  const int l16  = lane & 15;
  const int m0 = blockIdx.x * 128;
  const int n0 = blockIdx.y * 64;
  const int M16b = (m0 >> 4) + wave * 2;       // wave's row-tiles: M16b, M16b+1

  int wr[2], wc[2];
  #pragma unroll
  for (int i = 0; i < 2; i++) { int f = tid + i * 256; wr[i] = f >> 3; wc[i] = (f & 7) << 3; }

  f32x4 wreg[2];
  #pragma unroll
  for (int i = 0; i < 2; i++)
    wreg[i] = *(const f32x4*)&W[(size_t)(n0 + wr[i]) * K + wc[i]];

  short8 aCur[2][2], aNxt[2][2] = {};          // [row-tile t][ks]
  #pragma unroll
  for (int t = 0; t < 2; t++)
    #pragma unroll
    for (int ks = 0; ks < 2; ks++)
      aCur[t][ks] = *(const short8*)&Af[((size_t)(ks * 512 + M16b + t) << 9) + (lane << 3)];

  f32x4 acc[2][4] = {};

  for (int k0 = 0; k0 < K; k0 += 64) {
    __syncthreads();
    #pragma unroll
    for (int i = 0; i < 2; i++) *(f32x4*)&Ws[wr[i]][wc[i]] = wreg[i];
    __syncthreads();
    if (k0 + 64 < K) {
      #pragma unroll
      for (int i = 0; i < 2; i++)
        wreg[i] = *(const f32x4*)&W[(size_t)(n0 + wr[i]) * K + k0 + 64 + wc[i]];
      const int kbn = (k0 + 64) >> 5;
      #pragma unroll
      for (int t = 0; t < 2; t++)
        #pragma unroll
        for (int ks = 0; ks < 2; ks++)
          aNxt[t][ks] = *(const short8*)&Af[((size_t)((kbn + ks) * 512 + M16b + t) << 9) + (lane << 3)];
    }
    #pragma unroll
    for (int ks = 0; ks < 2; ks++) {
      const int kk = ks * 32 + quad * 8;
      short8 b0 = *(const short8*)&Ws[l16][kk];
      short8 b1 = *(const short8*)&Ws[16 + l16][kk];
      short8 b2 = *(const short8*)&Ws[32 + l16][kk];
      short8 b3 = *(const short8*)&Ws[48 + l16][kk];
      acc[0][0] = MFMA16(aCur[0][ks], b0, acc[0][0]);
      acc[0][1] = MFMA16(aCur[0][ks], b1, acc[0][1]);
      acc[0][2] = MFMA16(aCur[0][ks], b2, acc[0][2]);
      acc[0][3] = MFMA16(aCur[0][ks], b3, acc[0][3]);
      acc[1][0] = MFMA16(aCur[1][ks], b0, acc[1][0]);
      acc[1][1] = MFMA16(aCur[1][ks], b1, acc[1][1]);
      acc[1][2] = MFMA16(aCur[1][ks], b2, acc[1][2]);
      acc[1][3] = MFMA16(aCur[1][ks], b3, acc[1][3]);
    }
    #pragma unroll
    for (int t = 0; t < 2; t++)
      #pragma unroll
      for (int ks = 0; ks < 2; ks++)
        aCur[t][ks] = aNxt[t][ks];
  }

  float bv[4];
  #pragma unroll
  for (int j = 0; j < 4; j++) bv[j] = bias[n0 + j * 16 + l16];

  if (mode == 0) {
    const int sec = n0 / 768;
    const int h   = (n0 % 768) >> 6;
    unsigned short* dst = (sec == 0) ? out0 : ((sec == 1) ? out1 : out2);
    const float scl = (sec == 0) ? QSCALE : 1.0f;
    #pragma unroll
    for (int rg = 0; rg < 2; rg++) {
      #pragma unroll
      for (int r = 0; r < 4; r++) {
        int m  = m0 + wave * 32 + rg * 16 + quad * 4 + r;
        int b  = m >> 10, np = m & 1023;
        int bh = b * 12 + h;
        // within-64 key slot for the swapped-QK^T in-register P (V path)
        int s = (np & 35) | ((np & 12) << 1) | ((np & 16) >> 2);
        #pragma unroll
        for (int j = 0; j < 4; j++) {
          int d = j * 16 + l16;
          float v = (acc[rg][j][r] + bv[j]) * scl;
          if (sec == 0) {
            dst[((size_t)bh << 16) + ((size_t)np << 6) + d] = f2bf(v);
          } else if (sec == 1) {
            // K A-frag-major
            size_t kidx = ((size_t)((np >> 4) * 2 + (d >> 5)) << 9) +
                          ((((d >> 3) & 3) * 16 + (np & 15)) << 3) + (d & 7);
            dst[((size_t)bh << 16) + kidx] = f2bf(v);
          } else {
            // V B-frag-major, key perm folded
            size_t vidx = ((size_t)(((np >> 6) * 2 + (s >> 5)) * 4 + (d >> 4)) << 9) +
                          ((((s >> 3) & 3) * 16 + (d & 15)) << 3) + (s & 7);
            dst[((size_t)bh << 16) + vidx] = f2bf(v);
          }
        }
      }
    }
  } else {
    #pragma unroll
    for (int rg = 0; rg < 2; rg++) {
      #pragma unroll
      for (int r = 0; r < 4; r++) {
        int m = m0 + wave * 32 + rg * 16 + quad * 4 + r;
        #pragma unroll
        for (int j = 0; j < 4; j++)
          outf[(size_t)m * Ncols + n0 + j * 16 + l16] = acc[rg][j][r] + bv[j];
      }
    }
  }
}

// ---------------------------------------------------------------------------
// Kernel 3: flash attention, SWAPPED QK^T (S^T = K x Q), fully LDS-FREE:
// K and V were stored frag-major by the QKV GEMM, so every MFMA operand is a
// single coalesced 1KB/wave global load straight into registers.  NO LDS, NO
// __syncthreads -- waves are fully independent (latency-bound kernel: maximize
// scheduler freedom).  QBLK=64 (4 waves x 16 q-rows), grid 96x16.
// Natural register allocation (round-4 lesson: a forced VGPR cap spilled
// accumulators -> 225MB scratch traffic; never cap below the live set).
// Row-sum denominator via ones-column MFMA (round 3).
// Lane (l16,quad) after QK holds P[q=l16][key=16i+4*quad+r]; the V key perm
// (gemm mode 0) places key 16i+4q+r at PV A-frag slot ks*32+quad*8+(i&1)*4+r,
// ks=i>>1.
// ---------------------------------------------------------------------------
__global__ __launch_bounds__(256) void attn(
    const unsigned short* __restrict__ q,
    const unsigned short* __restrict__ k,
    const unsigned short* __restrict__ vt,
    unsigned short* __restrict__ of)
{
  const int tid  = threadIdx.x;
  const int wave = tid >> 6;
  const int lane = tid & 63;
  const int quad = lane >> 4;
  const int l16  = lane & 15;
  const int bh = blockIdx.x;
  const int q0 = blockIdx.y * 64;
  const unsigned short* qb = q  + ((size_t)bh << 16);
  const unsigned short* kb = k  + ((size_t)bh << 16);
  const unsigned short* vb = vt + ((size_t)bh << 16);

  // Q B-frags direct from global: B[n=l16][kdim = ks*32 + quad*8 + j]
  short8 bq[2];
  #pragma unroll
  for (int ks = 0; ks < 2; ks++)
    bq[ks] = *(const short8*)&qb[((size_t)(q0 + wave * 16 + l16) << 6) +
                                 ks * 32 + quad * 8];

  // all-ones bf16 B-fragment for the row-sum MFMA
  union { u32x4 w; short8 h; } onesu;
  onesu.w.x = 0x3F803F80u; onesu.w.y = 0x3F803F80u;
  onesu.w.z = 0x3F803F80u; onesu.w.w = 0x3F803F80u;
  const short8 onesb = onesu.h;

  f32x4 Oacc[4] = {};
  f32x4 lacc = {};

  union PAW { u32x4 w; short8 h; };

  for (int kt = 0; kt < 16; kt++) {
    // QK^T swapped: A = K frag-major tiles (global, coalesced), B = Q (regs).
    // K frag block index (np-tile, ks) = ((kt*4+i)*2 + ks); each block 512sh.
    f32x4 s[4] = {};
    #pragma unroll
    for (int ks = 0; ks < 2; ks++) {
      const unsigned short* gk = kb + ((size_t)((kt * 8 + ks)) << 9) + (lane << 3);
      short8 a0 = *(const short8*)&gk[0];
      short8 a1 = *(const short8*)&gk[1024];
      short8 a2 = *(const short8*)&gk[2048];
      short8 a3 = *(const short8*)&gk[3072];
      s[0] = MFMA16(a0, bq[ks], s[0]);
      s[1] = MFMA16(a1, bq[ks], s[1]);
      s[2] = MFMA16(a2, bq[ks], s[2]);
      s[3] = MFMA16(a3, bq[ks], s[3]);
    }

    // softmax (no max-subtraction; scale folded into Q) + in-register P frags
    f32x4 e[4];
    #pragma unroll
    for (int i = 0; i < 4; i++) {
      e[i].x = exp2f(s[i].x);
      e[i].y = exp2f(s[i].y);
      e[i].z = exp2f(s[i].z);
      e[i].w = exp2f(s[i].w);
    }
    short8 pa[2];
    #pragma unroll
    for (int ks = 0; ks < 2; ks++) {
      PAW pw;
      pw.w.x = cvtpk(e[2 * ks].x,     e[2 * ks].y);
      pw.w.y = cvtpk(e[2 * ks].z,     e[2 * ks].w);
      pw.w.z = cvtpk(e[2 * ks + 1].x, e[2 * ks + 1].y);
      pw.w.w = cvtpk(e[2 * ks + 1].z, e[2 * ks + 1].w);
      pa[ks] = pw.h;
    }

    // PV: A = P frags (regs), B = V frag-major tiles (global, coalesced).
    // V frag block index = ((kt*2+ks)*4 + jb); each block 512 shorts.
    // 5th MFMA per ks with B=ones accumulates row sums (denominator).
    #pragma unroll
    for (int ks = 0; ks < 2; ks++) {
      const unsigned short* gv = vb + ((size_t)((kt * 2 + ks) * 4) << 9) + (lane << 3);
      short8 v0 = *(const short8*)&gv[0];
      short8 v1 = *(const short8*)&gv[512];
      short8 v2 = *(const short8*)&gv[1024];
      short8 v3 = *(const short8*)&gv[1536];
      Oacc[0] = MFMA16(pa[ks], v0, Oacc[0]);
      Oacc[1] = MFMA16(pa[ks], v1, Oacc[1]);
      Oacc[2] = MFMA16(pa[ks], v2, Oacc[2]);
      Oacc[3] = MFMA16(pa[ks], v3, Oacc[3]);
      lacc    = MFMA16(pa[ks], onesb, lacc);
    }
  }

  // lacc[r] = full row sum for q-row quad*4+r (all l16 cols identical) --
  // already in the C/D indexing the epilogue uses; no cross-lane reduction.
  // O store in FRAG-MAJOR layout (proj GEMM's A-path):
  // row M = b*1024+np -> M16 = b*64 + (np>>4), l16m = np&15;
  // col = h*64 + j*16 + l16 -> kb = col>>5, qc = (col>>3)&3, jj = l16&7.
  const int b = bh / 12, h = bh - (bh / 12) * 12;
  #pragma unroll
  for (int r = 0; r < 4; r++) {
    float inv = 1.0f / lacc[r];
    int np  = q0 + wave * 16 + quad * 4 + r;
    int M16 = b * 64 + (np >> 4);
    int l16m = np & 15;
    #pragma unroll
    for (int j = 0; j < 4; j++) {
      int col = h * 64 + j * 16 + l16;
      int kb2 = col >> 5;
      int qc  = (col >> 3) & 3;
      size_t idx = ((size_t)(kb2 * 512 + M16) << 9) +
                   ((qc * 16 + l16m) << 3) + (l16 & 7);
      of[idx] = f2bf(Oacc[j][r] * inv);
    }
  }
}

// ---------------------------------------------------------------------------
extern "C" void kernel_launch(void* const* d_in, const int* in_sizes, int n_in,
                              void* d_out, int out_size, void* d_ws, size_t ws_size,
                              hipStream_t stream) {
  const float* x      = (const float*)d_in[0];
  const float* w_qkv  = (const float*)d_in[1];
  const float* b_qkv  = (const float*)d_in[2];
  const float* w_proj = (const float*)d_in[3];
  const float* b_proj = (const float*)d_in[4];
  const float* q_a    = (const float*)d_in[5];
  const float* q_b    = (const float*)d_in[6];
  const float* k_a    = (const float*)d_in[7];
  const float* k_b    = (const float*)d_in[8];
  const float* v_a    = (const float*)d_in[9];
  const float* v_b    = (const float*)d_in[10];
  const float* o_a    = (const float*)d_in[11];
  const float* o_b    = (const float*)d_in[12];

  char* ws = (char*)d_ws;
  unsigned short* wqkv_eff  = (unsigned short*)(ws + 0);          // 3,538,944
  unsigned short* wproj_eff = (unsigned short*)(ws + 3538944);    // 1,179,648
  unsigned short* xf        = (unsigned short*)(ws + 4718592);    // 12,582,912 (frag-major; reused as of)
  unsigned short* qd        = (unsigned short*)(ws + 17301504);   // 12,582,912
  unsigned short* kd        = (unsigned short*)(ws + 29884416);   // 12,582,912
  unsigned short* vtd       = (unsigned short*)(ws + 42467328);   // 12,582,912 (end 55,050,240)
  unsigned short* of        = xf;  // xf dead after QKV GEMM

  prep<<<dim3(6144 + 9216), dim3(256), 0, stream>>>(
      x, w_qkv, w_proj, q_a, q_b, k_a, k_b, v_a, v_b, o_a, o_b,
      xf, wqkv_eff, wproj_eff);

  gemm_bt<<<dim3(64, 36), dim3(256), 0, stream>>>(
      xf, wqkv_eff, b_qkv, qd, kd, vtd, nullptr, 768, 2304, 0);

  attn<<<dim3(96, 16), dim3(256), 0, stream>>>(qd, kd, vtd, of);

  gemm_bt<<<dim3(64, 12), dim3(256), 0, stream>>>(
      of, wproj_eff, b_proj, nullptr, nullptr, nullptr, (float*)d_out, 768, 768, 1);
}

// Round 6
// 215.815 us; speedup vs baseline: 1.5265x; 1.0057x over previous
//
#include <hip/hip_runtime.h>

typedef __attribute__((ext_vector_type(8))) short short8;
typedef __attribute__((ext_vector_type(4))) float f32x4;
typedef __attribute__((ext_vector_type(4))) unsigned short u16x4;
typedef __attribute__((ext_vector_type(4))) unsigned int u32x4;

#define MFMA16(a,b,c) __builtin_amdgcn_mfma_f32_16x16x32_bf16((a),(b),(c),0,0,0)

// 0.125 (attn scale) * log2(e), folded into Q at the QKV epilogue.
#define QSCALE 0.1803368801f

__device__ __forceinline__ unsigned short f2bf(float f) {
  unsigned int x = __float_as_uint(f);
  x += 0x7fffu + ((x >> 16) & 1u);
  return (unsigned short)(x >> 16);
}
// async 16B global -> LDS (dest = wave-uniform base + lane*16)
__device__ __forceinline__ void gload16(const unsigned short* g, unsigned short* l) {
  __builtin_amdgcn_global_load_lds(
      (const __attribute__((address_space(1))) unsigned int*)g,
      (__attribute__((address_space(3))) unsigned int*)l, 16, 0, 0);
}
// packed f32x2 -> bf16x2 (lo = a, hi = b), single VALU op
__device__ __forceinline__ unsigned int cvtpk(float a, float b) {
  unsigned int r;
  asm("v_cvt_pk_bf16_f32 %0, %1, %2" : "=v"(r) : "v"(a), "v"(b));
  return r;
}

// Fragment-major A layout: elem(m,k) -> xf[((k>>5)*512 + (m>>4))*512 +
// (((k>>3)&3)*16 + (m&15))*8 + (k&7)].  A wave's 16x32 MFMA A-frag (row-tile
// M16, k-block kb) is then 1 KB contiguous: base + lane*16B, one coalesced
// global_load_dwordx4 per lane. 512 = 8192/16 M16-tiles; kb = k/32.

// ---------------------------------------------------------------------------
// Kernel 1: prep = convert x -> frag-major bf16 (blocks < 6144) +
//                  build LoRA-folded weights (rest).
// ---------------------------------------------------------------------------
__global__ __launch_bounds__(256) void prep(
    const float* __restrict__ x,
    const float* __restrict__ w_qkv,
    const float* __restrict__ w_proj,
    const float* __restrict__ q_a, const float* __restrict__ q_b,
    const float* __restrict__ k_a, const float* __restrict__ k_b,
    const float* __restrict__ v_a, const float* __restrict__ v_b,
    const float* __restrict__ o_a, const float* __restrict__ o_b,
    unsigned short* __restrict__ xf,
    unsigned short* __restrict__ wqkv_eff,
    unsigned short* __restrict__ wproj_eff)
{
  int bid = blockIdx.x;
  if (bid < 6144) {
    int i4 = (bid * 256 + threadIdx.x) * 4;
    int m  = i4 / 768;
    int k4 = i4 - m * 768;             // 4 consecutive k, same 8-chunk half
    f32x4 v = *(const f32x4*)&x[i4];
    u16x4 o;
    o.x = f2bf(v.x); o.y = f2bf(v.y); o.z = f2bf(v.z); o.w = f2bf(v.w);
    int kb = k4 >> 5, qd = (k4 >> 3) & 3, j0 = k4 & 7;
    size_t idx = ((size_t)(kb * 512 + (m >> 4)) << 9) +
                 (((qd << 4) + (m & 15)) << 3) + j0;
    *(u16x4*)&xf[idx] = o;
    return;
  }
  const int QKV = 2304 * 768;
  int idx = (bid - 6144) * 256 + threadIdx.x;
  if (idx < QKV) {
    int n = idx / 768, c = idx - n * 768;
    int sec = n / 768;
    int nr = n - sec * 768;
    const float* a; const float* b;
    if (sec == 0)      { a = q_a; b = q_b; }
    else if (sec == 1) { a = k_a; b = k_b; }
    else               { a = v_a; b = v_b; }
    float acc = w_qkv[idx];
    #pragma unroll
    for (int r = 0; r < 8; r++)
      acc += b[nr * 8 + r] * a[r * 768 + c];
    wqkv_eff[idx] = f2bf(acc);
  } else {
    int i2 = idx - QKV;
    int n = i2 / 768, c = i2 - n * 768;
    float acc = w_proj[i2];
    #pragma unroll
    for (int r = 0; r < 8; r++)
      acc += o_b[n * 8 + r] * o_a[r * 768 + c];
    wproj_eff[i2] = f2bf(acc);
  }
}

// ---------------------------------------------------------------------------
// Kernel 2/4: C[M,Ncols] = A@W^T + bias. A in FRAG-MAJOR layout, loaded
// direct global->register (coalesced 1KB/wave), prefetched one iter ahead.
// W via padded-LDS VGPR-roundtrip with register prefetch.
// BM=128, BN=64, BK=64; 4 waves x 32 rows.
// mode 0 (QKV): Q*QSCALE -> q[BH][N][64] row-major;
//               K -> A-FRAG-MAJOR per bh: elem(np,d) at
//                    ((np>>4)*2 + d>>5)*512 + (((d>>3)&3)*16 + (np&15))*8 + (d&7)
//               V -> B-FRAG-MAJOR per bh with key perm s(np) folded:
//                    s = (np&35)|((np&12)<<1)|((np&16)>>2)  (within-64 slot);
//                    (((np>>6)*2 + (s>>5))*4 + (d>>4))*512 +
//                    (((s>>3)&3)*16 + (d&15))*8 + (s&7)
//               -> attn stages K/V tiles as contiguous 8KB gload16 runs and
//                  reads fragments as lane-contiguous 1KB ds_read_b128.
// mode 1: fp32 row-major store (final output).
// ---------------------------------------------------------------------------
__global__ __launch_bounds__(256) void gemm_bt(
    const unsigned short* __restrict__ Af,
    const unsigned short* __restrict__ W,
    const float* __restrict__ bias,
    unsigned short* __restrict__ out0,
    unsigned short* __restrict__ out1,
    unsigned short* __restrict__ out2,
    float* __restrict__ outf,
    int K, int Ncols, int mode)
{
  __shared__ alignas(16) unsigned short Ws[64][72];
  const int tid  = threadIdx.x;
  const int wave = tid >> 6;
  const int lane = tid & 63;
  const int quad = lane >> 4;
  const int l16  = lane & 15;
  const int m0 = blockIdx.x * 128;
  const int n0 = blockIdx.y * 64;
  const int M16b = (m0 >> 4) + wave * 2;       // wave's row-tiles: M16b, M16b+1

  int wr[2], wc[2];
  #pragma unroll
  for (int i = 0; i < 2; i++) { int f = tid + i * 256; wr[i] = f >> 3; wc[i] = (f & 7) << 3; }

  f32x4 wreg[2];
  #pragma unroll
  for (int i = 0; i < 2; i++)
    wreg[i] = *(const f32x4*)&W[(size_t)(n0 + wr[i]) * K + wc[i]];

  short8 aCur[2][2], aNxt[2][2] = {};          // [row-tile t][ks]
  #pragma unroll
  for (int t = 0; t < 2; t++)
    #pragma unroll
    for (int ks = 0; ks < 2; ks++)
      aCur[t][ks] = *(const short8*)&Af[((size_t)(ks * 512 + M16b + t) << 9) + (lane << 3)];

  f32x4 acc[2][4] = {};

  for (int k0 = 0; k0 < K; k0 += 64) {
    __syncthreads();
    #pragma unroll
    for (int i = 0; i < 2; i++) *(f32x4*)&Ws[wr[i]][wc[i]] = wreg[i];
    __syncthreads();
    if (k0 + 64 < K) {
      #pragma unroll
      for (int i = 0; i < 2; i++)
        wreg[i] = *(const f32x4*)&W[(size_t)(n0 + wr[i]) * K + k0 + 64 + wc[i]];
      const int kbn = (k0 + 64) >> 5;
      #pragma unroll
      for (int t = 0; t < 2; t++)
        #pragma unroll
        for (int ks = 0; ks < 2; ks++)
          aNxt[t][ks] = *(const short8*)&Af[((size_t)((kbn + ks) * 512 + M16b + t) << 9) + (lane << 3)];
    }
    #pragma unroll
    for (int ks = 0; ks < 2; ks++) {
      const int kk = ks * 32 + quad * 8;
      short8 b0 = *(const short8*)&Ws[l16][kk];
      short8 b1 = *(const short8*)&Ws[16 + l16][kk];
      short8 b2 = *(const short8*)&Ws[32 + l16][kk];
      short8 b3 = *(const short8*)&Ws[48 + l16][kk];
      acc[0][0] = MFMA16(aCur[0][ks], b0, acc[0][0]);
      acc[0][1] = MFMA16(aCur[0][ks], b1, acc[0][1]);
      acc[0][2] = MFMA16(aCur[0][ks], b2, acc[0][2]);
      acc[0][3] = MFMA16(aCur[0][ks], b3, acc[0][3]);
      acc[1][0] = MFMA16(aCur[1][ks], b0, acc[1][0]);
      acc[1][1] = MFMA16(aCur[1][ks], b1, acc[1][1]);
      acc[1][2] = MFMA16(aCur[1][ks], b2, acc[1][2]);
      acc[1][3] = MFMA16(aCur[1][ks], b3, acc[1][3]);
    }
    #pragma unroll
    for (int t = 0; t < 2; t++)
      #pragma unroll
      for (int ks = 0; ks < 2; ks++)
        aCur[t][ks] = aNxt[t][ks];
  }

  float bv[4];
  #pragma unroll
  for (int j = 0; j < 4; j++) bv[j] = bias[n0 + j * 16 + l16];

  if (mode == 0) {
    const int sec = n0 / 768;
    const int h   = (n0 % 768) >> 6;
    unsigned short* dst = (sec == 0) ? out0 : ((sec == 1) ? out1 : out2);
    const float scl = (sec == 0) ? QSCALE : 1.0f;
    #pragma unroll
    for (int rg = 0; rg < 2; rg++) {
      #pragma unroll
      for (int r = 0; r < 4; r++) {
        int m  = m0 + wave * 32 + rg * 16 + quad * 4 + r;
        int b  = m >> 10, np = m & 1023;
        int bh = b * 12 + h;
        // within-64 key slot for the swapped-QK^T in-register P (V path)
        int s = (np & 35) | ((np & 12) << 1) | ((np & 16) >> 2);
        #pragma unroll
        for (int j = 0; j < 4; j++) {
          int d = j * 16 + l16;
          float v = (acc[rg][j][r] + bv[j]) * scl;
          if (sec == 0) {
            dst[((size_t)bh << 16) + ((size_t)np << 6) + d] = f2bf(v);
          } else if (sec == 1) {
            // K A-frag-major
            size_t kidx = ((size_t)((np >> 4) * 2 + (d >> 5)) << 9) +
                          ((((d >> 3) & 3) * 16 + (np & 15)) << 3) + (d & 7);
            dst[((size_t)bh << 16) + kidx] = f2bf(v);
          } else {
            // V B-frag-major, key perm folded
            size_t vidx = ((size_t)(((np >> 6) * 2 + (s >> 5)) * 4 + (d >> 4)) << 9) +
                          ((((s >> 3) & 3) * 16 + (d & 15)) << 3) + (s & 7);
            dst[((size_t)bh << 16) + vidx] = f2bf(v);
          }
        }
      }
    }
  } else {
    #pragma unroll
    for (int rg = 0; rg < 2; rg++) {
      #pragma unroll
      for (int r = 0; r < 4; r++) {
        int m = m0 + wave * 32 + rg * 16 + quad * 4 + r;
        #pragma unroll
        for (int j = 0; j < 4; j++)
          outf[(size_t)m * Ncols + n0 + j * 16 + l16] = acc[rg][j][r] + bv[j];
      }
    }
  }
}

// ---------------------------------------------------------------------------
// Kernel 3: flash attention, SWAPPED QK^T (S^T = K x Q), frag-major K/V
// staged through a double-buffered LDS (round-6: recombines round-3's
// once-per-block staging -- round-5's LDS-free variant made each WAVE pull
// 256KB through L2, ~70% of the per-CU L2 ceiling -- with round-5's
// frag-major layouts).  Each kt-tile of K and V is one CONTIGUOUS 8KB run:
// staged by 2 gload16 calls (dest tid*16B, linear), read back as
// lane-contiguous 1KB ds_read_b128 -- the optimal LDS pattern, no swizzle.
// QBLK=64 (4 waves x 16 q-rows), grid 96x16; LDS 32KB -> 5 blocks/CU.
// Natural register allocation (round-4 lesson: never cap below live set).
// Row-sum denominator via ones-column MFMA (round 3).
// Lane (l16,quad) after QK holds P[q=l16][key=16i+4*quad+r]; the V key perm
// (gemm mode 0) places key 16i+4q+r at PV A-frag slot ks*32+quad*8+(i&1)*4+r,
// ks=i>>1.
// ---------------------------------------------------------------------------
__global__ __launch_bounds__(256) void attn(
    const unsigned short* __restrict__ q,
    const unsigned short* __restrict__ k,
    const unsigned short* __restrict__ vt,
    unsigned short* __restrict__ of)
{
  __shared__ alignas(16) unsigned short Ks2[2][4096];  // 2 x 8 KB (frag-major tile)
  __shared__ alignas(16) unsigned short Vs2[2][4096];  // 2 x 8 KB
  const int tid  = threadIdx.x;
  const int wave = tid >> 6;
  const int lane = tid & 63;
  const int quad = lane >> 4;
  const int l16  = lane & 15;
  const int bh = blockIdx.x;
  const int q0 = blockIdx.y * 64;
  const unsigned short* qb = q  + ((size_t)bh << 16);
  const unsigned short* kb = k  + ((size_t)bh << 16);
  const unsigned short* vb = vt + ((size_t)bh << 16);

  // stage tile kt: K at kb + kt*4096 (shorts), V at vb + kt*4096 -- both
  // contiguous 8KB.  Thread t covers shorts [t*8, t*8+8) and [2048+t*8, ...).
  const int t8 = tid * 8;
  gload16(kb + t8,        &Ks2[0][t8]);
  gload16(kb + 2048 + t8, &Ks2[0][2048 + t8]);
  gload16(vb + t8,        &Vs2[0][t8]);
  gload16(vb + 2048 + t8, &Vs2[0][2048 + t8]);

  // Q B-frags direct from global: B[n=l16][kdim = ks*32 + quad*8 + j]
  short8 bq[2];
  #pragma unroll
  for (int ks = 0; ks < 2; ks++)
    bq[ks] = *(const short8*)&qb[((size_t)(q0 + wave * 16 + l16) << 6) +
                                 ks * 32 + quad * 8];

  // all-ones bf16 B-fragment for the row-sum MFMA
  union { u32x4 w; short8 h; } onesu;
  onesu.w.x = 0x3F803F80u; onesu.w.y = 0x3F803F80u;
  onesu.w.z = 0x3F803F80u; onesu.w.w = 0x3F803F80u;
  const short8 onesb = onesu.h;

  f32x4 Oacc[4] = {};
  f32x4 lacc = {};

  union PAW { u32x4 w; short8 h; };

  for (int kt = 0; kt < 16; kt++) {
    const int p = kt & 1;
    __syncthreads();   // implicit vmcnt(0): stage of [p] complete; all waves done with [1-p]
    if (kt < 15) {
      const unsigned short* gkn = kb + (kt + 1) * 4096 + t8;
      const unsigned short* gvn = vb + (kt + 1) * 4096 + t8;
      gload16(gkn,        &Ks2[1 - p][t8]);
      gload16(gkn + 2048, &Ks2[1 - p][2048 + t8]);
      gload16(gvn,        &Vs2[1 - p][t8]);
      gload16(gvn + 2048, &Vs2[1 - p][2048 + t8]);
    }

    // QK^T swapped: A = K frag (LDS, lane-contiguous), B = Q (regs).
    // K in-tile frag block = i*2 + ks; s[i] reg r = S[key=16i+4*quad+r][q=l16]
    f32x4 s[4] = {};
    #pragma unroll
    for (int ks = 0; ks < 2; ks++) {
      const unsigned short* lk = &Ks2[p][ks * 512 + lane * 8];
      short8 a0 = *(const short8*)&lk[0];
      short8 a1 = *(const short8*)&lk[1024];
      short8 a2 = *(const short8*)&lk[2048];
      short8 a3 = *(const short8*)&lk[3072];
      s[0] = MFMA16(a0, bq[ks], s[0]);
      s[1] = MFMA16(a1, bq[ks], s[1]);
      s[2] = MFMA16(a2, bq[ks], s[2]);
      s[3] = MFMA16(a3, bq[ks], s[3]);
    }

    // softmax (no max-subtraction; scale folded into Q) + in-register P frags
    f32x4 e[4];
    #pragma unroll
    for (int i = 0; i < 4; i++) {
      e[i].x = exp2f(s[i].x);
      e[i].y = exp2f(s[i].y);
      e[i].z = exp2f(s[i].z);
      e[i].w = exp2f(s[i].w);
    }
    short8 pa[2];
    #pragma unroll
    for (int ks = 0; ks < 2; ks++) {
      PAW pw;
      pw.w.x = cvtpk(e[2 * ks].x,     e[2 * ks].y);
      pw.w.y = cvtpk(e[2 * ks].z,     e[2 * ks].w);
      pw.w.z = cvtpk(e[2 * ks + 1].x, e[2 * ks + 1].y);
      pw.w.w = cvtpk(e[2 * ks + 1].z, e[2 * ks + 1].w);
      pa[ks] = pw.h;
    }

    // PV: A = P frags (regs), B = V frag (LDS, lane-contiguous).
    // V in-tile frag block = ks*4 + j.  5th MFMA per ks: row sums (denom).
    #pragma unroll
    for (int ks = 0; ks < 2; ks++) {
      const unsigned short* lv = &Vs2[p][ks * 2048 + lane * 8];
      short8 v0 = *(const short8*)&lv[0];
      short8 v1 = *(const short8*)&lv[512];
      short8 v2 = *(const short8*)&lv[1024];
      short8 v3 = *(const short8*)&lv[1536];
      Oacc[0] = MFMA16(pa[ks], v0, Oacc[0]);
      Oacc[1] = MFMA16(pa[ks], v1, Oacc[1]);
      Oacc[2] = MFMA16(pa[ks], v2, Oacc[2]);
      Oacc[3] = MFMA16(pa[ks], v3, Oacc[3]);
      lacc    = MFMA16(pa[ks], onesb, lacc);
    }
  }

  // lacc[r] = full row sum for q-row quad*4+r (all l16 cols identical) --
  // already in the C/D indexing the epilogue uses; no cross-lane reduction.
  // O store in FRAG-MAJOR layout (proj GEMM's A-path):
  // row M = b*1024+np -> M16 = b*64 + (np>>4), l16m = np&15;
  // col = h*64 + j*16 + l16 -> kb = col>>5, qc = (col>>3)&3, jj = l16&7.
  const int b = bh / 12, h = bh - (bh / 12) * 12;
  #pragma unroll
  for (int r = 0; r < 4; r++) {
    float inv = 1.0f / lacc[r];
    int np  = q0 + wave * 16 + quad * 4 + r;
    int M16 = b * 64 + (np >> 4);
    int l16m = np & 15;
    #pragma unroll
    for (int j = 0; j < 4; j++) {
      int col = h * 64 + j * 16 + l16;
      int kb2 = col >> 5;
      int qc  = (col >> 3) & 3;
      size_t idx = ((size_t)(kb2 * 512 + M16) << 9) +
                   ((qc * 16 + l16m) << 3) + (l16 & 7);
      of[idx] = f2bf(Oacc[j][r] * inv);
    }
  }
}

// ---------------------------------------------------------------------------
extern "C" void kernel_launch(void* const* d_in, const int* in_sizes, int n_in,
                              void* d_out, int out_size, void* d_ws, size_t ws_size,
                              hipStream_t stream) {
  const float* x      = (const float*)d_in[0];
  const float* w_qkv  = (const float*)d_in[1];
  const float* b_qkv  = (const float*)d_in[2];
  const float* w_proj = (const float*)d_in[3];
  const float* b_proj = (const float*)d_in[4];
  const float* q_a    = (const float*)d_in[5];
  const float* q_b    = (const float*)d_in[6];
  const float* k_a    = (const float*)d_in[7];
  const float* k_b    = (const float*)d_in[8];
  const float* v_a    = (const float*)d_in[9];
  const float* v_b    = (const float*)d_in[10];
  const float* o_a    = (const float*)d_in[11];
  const float* o_b    = (const float*)d_in[12];

  char* ws = (char*)d_ws;
  unsigned short* wqkv_eff  = (unsigned short*)(ws + 0);          // 3,538,944
  unsigned short* wproj_eff = (unsigned short*)(ws + 3538944);    // 1,179,648
  unsigned short* xf        = (unsigned short*)(ws + 4718592);    // 12,582,912 (frag-major; reused as of)
  unsigned short* qd        = (unsigned short*)(ws + 17301504);   // 12,582,912
  unsigned short* kd        = (unsigned short*)(ws + 29884416);   // 12,582,912
  unsigned short* vtd       = (unsigned short*)(ws + 42467328);   // 12,582,912 (end 55,050,240)
  unsigned short* of        = xf;  // xf dead after QKV GEMM

  prep<<<dim3(6144 + 9216), dim3(256), 0, stream>>>(
      x, w_qkv, w_proj, q_a, q_b, k_a, k_b, v_a, v_b, o_a, o_b,
      xf, wqkv_eff, wproj_eff);

  gemm_bt<<<dim3(64, 36), dim3(256), 0, stream>>>(
      xf, wqkv_eff, b_qkv, qd, kd, vtd, nullptr, 768, 2304, 0);

  attn<<<dim3(96, 16), dim3(256), 0, stream>>>(qd, kd, vtd, of);

  gemm_bt<<<dim3(64, 12), dim3(256), 0, stream>>>(
      of, wproj_eff, b_proj, nullptr, nullptr, nullptr, (float*)d_out, 768, 768, 1);
}